// Round 17
// baseline (73.117 us; speedup 1.0000x reference)
//
#include <hip/hip_runtime.h>
#include <hip/hip_bf16.h>
#include <float.h>
#include <math.h>

// Problem constants
#define Bn   8
#define Cn   512
#define Tn   4096
#define Kn   512      // codes per sub-codebook
#define SUBn 128      // dims per sub-codebook
#define TOTELEM 16777216  // B*C*T
#define TILES 2       // t-tiles per block (grid 1024; whole block prefetched upfront)
#define BRT  64       // t-rows per tile

typedef __attribute__((ext_vector_type(8))) short bf16x8;   // 8 bf16 = 4 VGPRs
typedef __attribute__((ext_vector_type(4))) float f32x4;    // MFMA acc
typedef __attribute__((ext_vector_type(4))) float nf4;      // native float4

// LDS-only barrier: waits ds ops, leaves vmcnt (global prefetch/stores) in flight.
#define BARRIER() asm volatile("s_waitcnt lgkmcnt(0)\ns_barrier" ::: "memory")

static __device__ inline unsigned int pack2(float a, float b) {
  union { __hip_bfloat162 h; unsigned int u; } cv;
  cv.h = __float22bfloat162_rn(make_float2(a, b));
  return cv.u;
}

// ---------------- precompute: wPack (bf16 fragment order) + ||w||^2 -----------
// Fragment layout (per 16-c block fb = cBlk*16 + ks*4 + g):
//   element offset = fb*128 + (c&15)*8 + (k&7)
__global__ __launch_bounds__(256) void vq4_pre(
    const float* __restrict__ w0, const float* __restrict__ w1,
    const float* __restrict__ w2_, const float* __restrict__ w3,
    unsigned short* __restrict__ wPack, float* __restrict__ w2a)
{
  const int s  = blockIdx.x >> 3;    // sub-codebook
  const int ch = blockIdx.x & 7;     // 64-c chunk
  const int tid = threadIdx.x;
  const float* w = (s == 0) ? w0 : (s == 1) ? w1 : (s == 2) ? w2_ : w3;
  unsigned short* dst = wPack + (size_t)s * Kn * SUBn;

  for (int it = 0; it < 8; ++it) {
    int cell = ch * 2048 + tid + 256 * it;   // 2048 float4 cells per chunk
    int c = cell >> 5;
    int k4 = (cell & 31) * 4;
    nf4 v = *(const nf4*)(w + (size_t)c * SUBn + k4);
    int ks = k4 >> 5, g = (k4 >> 3) & 3, kLo = k4 & 7;
    int fb = (c >> 4) * 16 + ks * 4 + g;
    int off = fb * 128 + (c & 15) * 8 + kLo;
    uint2 p;
    p.x = pack2(v.x, v.y);
    p.y = pack2(v.z, v.w);
    *(uint2*)(dst + off) = p;
  }
  if (tid < 64) {
    int c = ch * 64 + tid;
    const float* row = w + (size_t)c * SUBn;
    float acc = 0.f;
    #pragma unroll
    for (int k = 0; k < SUBn; k += 4) {
      nf4 v = *(const nf4*)(row + k);
      acc = fmaf(v.x, v.x, fmaf(v.y, v.y, fmaf(v.z, v.z, fmaf(v.w, v.w, acc))));
    }
    w2a[s * Kn + c] = acc;
  }
}

// ---------------- main: 2-tile block, full upfront prefetch, 3 barriers -------
// 256 threads (4 waves). Wave owns a 128-code slice in registers (wA[8][4]).
// D = mfma(A=w, B=x, C=-w^2/2); argmin(w2-2dot) == argmax(D); per-tile result
// via LDS atomicMax of sortable u64 keys into keyb[tile][t].
// r17: BOTH tiles' x loads issued in the prologue (P,Q) — pack0 waits only P
// (Q stays in flight, in-order vmcnt), pack1's Q lands under P2(0) -> zero
// mid-block load stalls. tileA/tileB each written once (no reuse hazard).
// Epilogue (idx/gather/out/loss) deferred past all compute. setprio on MFMA.
// launch_bounds(256,1): the ONLY config that avoids spills for this footprint.
__global__ __launch_bounds__(256, 1) void vq4_main(
    const float* __restrict__ x,
    const unsigned short* __restrict__ wPack,
    const float* __restrict__ w2a,
    const float* __restrict__ w0, const float* __restrict__ w1,
    const float* __restrict__ w2_, const float* __restrict__ w3,
    float* __restrict__ out,
    int* __restrict__ idxBuf, float* __restrict__ lossSum)
{
  __shared__ unsigned char tileA[16384];       // x-tile bf16 [t 64][k 128], swizzled
  __shared__ unsigned char tileB[16384];
  __shared__ unsigned long long keyb[TILES][BRT];  // argmax keys, one buf per tile
  __shared__ float w2L[512];                   // -0.5 * ||w_c||^2 for this sub
  __shared__ float wl[4];

  const int bx  = blockIdx.x;      // 32 tile-groups
  const int b   = blockIdx.y;      // 8
  const int sub = blockIdx.z;      // 4
  const int tid = threadIdx.x;
  const int wid = tid >> 6, lane = tid & 63;
  const int r16_ = lane & 15, g4 = lane >> 4;

  // stage mapping: tid -> (sk8 = tid>>4, sq = tid&15); t = sq*4+j
  const int sq  = tid & 15;
  const int sk8 = tid >> 4;

  const float* xb = x + ((size_t)b * Cn + sub * SUBn) * Tn;
  const unsigned short* wp = wPack + (size_t)sub * Kn * SUBn + lane * 8;
  const float* w2s = w2a + sub * Kn;
  const float* worig = (sub == 0) ? w0 : (sub == 1) ? w1 : (sub == 2) ? w2_ : w3;
  float* outb = out + ((size_t)b * Cn + sub * SUBn) * Tn;
  int* idxOut = idxBuf + ((size_t)b * 4 + sub) * Tn;

  // ---- prologue: zero key buffers; stage -0.5*w2 into LDS ----
  if (tid < TILES * BRT)
    ((unsigned long long*)keyb)[tid] = 0ULL;
  if (tid < 128) {
    nf4 v = *(const nf4*)(w2s + 4 * tid);
    *(nf4*)&w2L[4 * tid] = -0.5f * v;
  }

  // ---- prologue: issue BOTH tiles' x loads (in-order: P first, then Q) ----
  nf4 P[8], Q[8];
  {
    const float* src = xb + (size_t)(sk8 * 8) * Tn + (bx * TILES) * BRT + 4 * sq;
    #pragma unroll
    for (int i = 0; i < 8; ++i)
      P[i] = *(const nf4*)(src + (size_t)i * Tn);
    #pragma unroll
    for (int i = 0; i < 8; ++i)
      Q[i] = *(const nf4*)(src + BRT + (size_t)i * Tn);
  }

  // ---- load this wave's 128-code slice into registers (once per block) ----
  bf16x8 wA[8][4];
  #pragma unroll
  for (int ct = 0; ct < 8; ++ct)
    #pragma unroll
    for (int ks = 0; ks < 4; ++ks)
      wA[ct][ks] = *(const bf16x8*)(wp + (size_t)((wid * 8 + ct) * 4 + ks) * 512);

  float lossAcc = 0.f;

  // pack: register tile -> bf16 LDS tile (+ sum x^2)
  auto packTile = [&](const nf4* R, unsigned char* buf) {
    float xs = 0.f;
    #pragma unroll
    for (int i = 0; i < 8; ++i)
      xs += R[i].x * R[i].x + R[i].y * R[i].y + R[i].z * R[i].z + R[i].w * R[i].w;
    lossAcc += xs;
    #pragma unroll
    for (int j = 0; j < 4; ++j) {
      int t = 4 * sq + j;
      uint4 pv;
      pv.x = pack2(R[0][j], R[1][j]);
      pv.y = pack2(R[2][j], R[3][j]);
      pv.z = pack2(R[4][j], R[5][j]);
      pv.w = pack2(R[6][j], R[7][j]);
      int waddr = t * 256 + ((sk8 * 16) ^ ((t & 15) << 4));
      *(uint4*)(buf + waddr) = pv;
    }
  };

  // compute: 4 t-groups; 32 MFMA + tree-argmax + key atomicMax
  auto computeTile = [&](const unsigned char* buf, unsigned long long* keyrow) {
    __builtin_amdgcn_s_setprio(1);
    #pragma unroll
    for (int tg = 0; tg < 4; ++tg) {
      const int t = tg * 16 + r16_;
      bf16x8 xB[4];
      #pragma unroll
      for (int ks = 0; ks < 4; ++ks) {
        int aaddr = t * 256 + ((((ks * 4 + g4) * 16)) ^ (r16_ << 4));
        xB[ks] = *(const bf16x8*)(buf + aaddr);
      }
      f32x4 acc[8];
      #pragma unroll
      for (int ct = 0; ct < 8; ++ct)
        acc[ct] = *(const f32x4*)&w2L[wid * 128 + ct * 16 + g4 * 4];
      #pragma unroll
      for (int ks = 0; ks < 4; ++ks)
        #pragma unroll
        for (int ct = 0; ct < 8; ++ct)
          acc[ct] = __builtin_amdgcn_mfma_f32_16x16x32_bf16(
              wA[ct][ks], xB[ks], acc[ct], 0, 0, 0);

      // per-ct serial argmax over r (c-ascending, keep-left on ties)
      float cv[8]; int cc_[8];
      #pragma unroll
      for (int ct = 0; ct < 8; ++ct) {
        float bv = acc[ct][0]; int br = ct * 4;
        #pragma unroll
        for (int r = 1; r < 4; ++r)
          if (acc[ct][r] > bv) { bv = acc[ct][r]; br = ct * 4 + r; }
        cv[ct] = bv; cc_[ct] = br;
      }
      // 3-level tree over the 8 ct-chains (c-ascending, keep-left on ties)
      #pragma unroll
      for (int s = 4; s >= 1; s >>= 1)
        #pragma unroll
        for (int i = 0; i < s; ++i)
          if (cv[i + s] > cv[i]) { cv[i] = cv[i + s]; cc_[i] = cc_[i + s]; }

      int code = cc_[0];                        // 0..31 (ct*4+r)
      int bi = wid * 128 + (code >> 2) * 16 + g4 * 4 + (code & 3);
      unsigned long long k64 =
          (unsigned long long)__double_as_longlong((double)cv[0] + 16.0) |
          (unsigned long long)(511 - bi);
      atomicMax(&keyrow[t], k64);
    }
    __builtin_amdgcn_s_setprio(0);
  };

  // ---- tile 0: pack P (waits P only; Q stays in flight) -> compute ----
  packTile(P, tileA);
  BARRIER();                        // tileA + w2L + keyb ready
  computeTile(tileA, keyb[0]);

  // ---- tile 1: pack Q (landed under compute 0) -> compute ----
  packTile(Q, tileB);
  BARRIER();                        // tileB ready
  computeTile(tileB, keyb[1]);

  BARRIER();                        // all keys final

  // ---- epilogue: decode keys; idx stores; gather + out stores; loss ----
  #pragma unroll
  for (int itile = 0; itile < TILES; ++itile) {
    const int t0 = (bx * TILES + itile) * BRT;
    const int gt = lane;             // t within tile
    const int kc = wid;              // 32-k chunk per wave
    unsigned long long kk = keyb[itile][gt];
    int bi = 511 - (int)(kk & 0x1FFULL);
    if (tid < BRT) {
      idxOut[t0 + tid] = bi;         // coalesced 256 B plain store
      double vd = __longlong_as_double((long long)(kk & ~0x1FFULL));
      lossAcc += -2.0f * (float)(vd - 16.0);   // min(w2-2s.w) = -2*max(D)
    }
    const float* wrow = worig + (size_t)bi * SUBn + kc * 32;
    float* op = outb + (size_t)(kc * 32) * Tn + t0 + gt;
    #pragma unroll
    for (int i = 0; i < 8; ++i) {
      nf4 wv = *(const nf4*)(wrow + 4 * i);
      op[(size_t)(4 * i + 0) * Tn] = wv.x;
      op[(size_t)(4 * i + 1) * Tn] = wv.y;
      op[(size_t)(4 * i + 2) * Tn] = wv.z;
      op[(size_t)(4 * i + 3) * Tn] = wv.w;
    }
  }

  // ---- block loss reduction -> one atomic ----
  #pragma unroll
  for (int off = 32; off; off >>= 1) lossAcc += __shfl_down(lossAcc, off, 64);
  if (lane == 0) wl[wid] = lossAcc;
  BARRIER();
  if (tid == 0)
    atomicAdd(lossSum, wl[0] + wl[1] + wl[2] + wl[3]);
}

// ---------------- hist: LDS histogram of idxBuf (off main's critical path) ----
__global__ __launch_bounds__(256) void vq4_hist(
    const int* __restrict__ idxBuf, int* __restrict__ hist)
{
  __shared__ int h[512];
  const int b = blockIdx.x >> 2;
  const int s = blockIdx.x & 3;
  const int tid = threadIdx.x;
  h[tid] = 0; h[tid + 256] = 0;
  __syncthreads();
  const int* p = idxBuf + ((size_t)b * 4 + s) * Tn;
  #pragma unroll
  for (int it = 0; it < 4; ++it) {
    int4 v = *(const int4*)(p + 4 * (tid + 256 * it));
    atomicAdd(&h[v.x], 1); atomicAdd(&h[v.y], 1);
    atomicAdd(&h[v.z], 1); atomicAdd(&h[v.w], 1);
  }
  __syncthreads();
  atomicAdd(&hist[s * Kn + tid], h[tid]);
  atomicAdd(&hist[s * Kn + tid + 256], h[tid + 256]);
}

// ---------------- finalize: vq_loss + perplexity ----------------
__global__ __launch_bounds__(256) void vq4_fin(
    const int* __restrict__ hist, const float* __restrict__ lossSum,
    float* __restrict__ out)
{
  const int tid = threadIdx.x;
  float local[4] = {0.f, 0.f, 0.f, 0.f};
  #pragma unroll
  for (int it = 0; it < 8; ++it) {
    int slot = tid + 256 * it;       // 2048 = 4 x 512
    int s = slot >> 9;
    float p = (float)hist[slot] * (1.0f / 32768.0f);
    local[s] += -p * logf(p + 1e-10f);
  }
  __shared__ float red[4][4];
  int lane = tid & 63, wv = tid >> 6;
  #pragma unroll
  for (int s = 0; s < 4; ++s) {
    float v = local[s];
    for (int off = 32; off; off >>= 1) v += __shfl_down(v, off, 64);
    if (lane == 0) red[s][wv] = v;
  }
  __syncthreads();
  if (tid == 0) {
    float loss = 1.25f * lossSum[0] * (1.0f / (float)TOTELEM);
    float perp = 0.f;
    #pragma unroll
    for (int s = 0; s < 4; ++s)
      perp += expf(red[s][0] + red[s][1] + red[s][2] + red[s][3]);
    out[TOTELEM]     = loss;
    out[TOTELEM + 1] = perp;
  }
}

extern "C" void kernel_launch(void* const* d_in, const int* in_sizes, int n_in,
                              void* d_out, int out_size, void* d_ws, size_t ws_size,
                              hipStream_t stream) {
  const float* x  = (const float*)d_in[0];
  const float* w1 = (const float*)d_in[1];
  const float* w2 = (const float*)d_in[2];
  const float* w3 = (const float*)d_in[3];
  const float* w4 = (const float*)d_in[4];
  float* out = (float*)d_out;

  // Disjoint workspace layout
  char* ws = (char*)d_ws;
  float* lossSum = (float*)ws;                            // [0, 16)
  int*   hist    = (int*)(ws + 16);                       // [16, 8208)
  float* w2a     = (float*)(ws + 16384);                  // [16K, 24K)
  unsigned short* wPack = (unsigned short*)(ws + 32768);  // [32K, 544K)
  int*   idxBuf  = (int*)(ws + 1048576);                  // [1M, 1.5M)

  // zero accumulators (hist + lossSum) every call — ws is not re-poisoned
  (void)hipMemsetAsync(d_ws, 0, 8208, stream);

  vq4_pre<<<dim3(32), dim3(256), 0, stream>>>(w1, w2, w3, w4, wPack, w2a);
  vq4_main<<<dim3(Tn / BRT / TILES, Bn, 4), dim3(256), 0, stream>>>(
      x, wPack, w2a, w1, w2, w3, w4, out, idxBuf, lossSum);
  vq4_hist<<<dim3(32), dim3(256), 0, stream>>>(idxBuf, hist);
  vq4_fin<<<dim3(1), dim3(256), 0, stream>>>(hist, lossSum, out);
}

// Round 18
// 62.823 us; speedup vs baseline: 1.1638x; 1.1638x over previous
//
#include <hip/hip_runtime.h>
#include <hip/hip_bf16.h>
#include <float.h>
#include <math.h>

// Problem constants
#define Bn   8
#define Cn   512
#define Tn   4096
#define Kn   512      // codes per sub-codebook
#define SUBn 128      // dims per sub-codebook
#define TOTELEM 16777216  // B*C*T
#define TILES 4       // t-tiles per block (r16 best-known config)
#define BRT  64       // t-rows per tile

typedef __attribute__((ext_vector_type(8))) short bf16x8;   // 8 bf16 = 4 VGPRs
typedef __attribute__((ext_vector_type(4))) float f32x4;    // MFMA acc
typedef __attribute__((ext_vector_type(4))) float nf4;      // native float4

// LDS-only barrier: waits ds ops, leaves vmcnt (global prefetch/stores) in flight.
#define BARRIER() asm volatile("s_waitcnt lgkmcnt(0)\ns_barrier" ::: "memory")

static __device__ inline unsigned int pack2(float a, float b) {
  union { __hip_bfloat162 h; unsigned int u; } cv;
  cv.h = __float22bfloat162_rn(make_float2(a, b));
  return cv.u;
}

// ---------------- precompute: wPack (bf16 fragment order) + ||w||^2 -----------
// Fragment layout (per 16-c block fb = cBlk*16 + ks*4 + g):
//   element offset = fb*128 + (c&15)*8 + (k&7)
__global__ __launch_bounds__(256) void vq4_pre(
    const float* __restrict__ w0, const float* __restrict__ w1,
    const float* __restrict__ w2_, const float* __restrict__ w3,
    unsigned short* __restrict__ wPack, float* __restrict__ w2a)
{
  const int s  = blockIdx.x >> 3;    // sub-codebook
  const int ch = blockIdx.x & 7;     // 64-c chunk
  const int tid = threadIdx.x;
  const float* w = (s == 0) ? w0 : (s == 1) ? w1 : (s == 2) ? w2_ : w3;
  unsigned short* dst = wPack + (size_t)s * Kn * SUBn;

  for (int it = 0; it < 8; ++it) {
    int cell = ch * 2048 + tid + 256 * it;   // 2048 float4 cells per chunk
    int c = cell >> 5;
    int k4 = (cell & 31) * 4;
    nf4 v = *(const nf4*)(w + (size_t)c * SUBn + k4);
    int ks = k4 >> 5, g = (k4 >> 3) & 3, kLo = k4 & 7;
    int fb = (c >> 4) * 16 + ks * 4 + g;
    int off = fb * 128 + (c & 15) * 8 + kLo;
    uint2 p;
    p.x = pack2(v.x, v.y);
    p.y = pack2(v.z, v.w);
    *(uint2*)(dst + off) = p;
  }
  if (tid < 64) {
    int c = ch * 64 + tid;
    const float* row = w + (size_t)c * SUBn;
    float acc = 0.f;
    #pragma unroll
    for (int k = 0; k < SUBn; k += 4) {
      nf4 v = *(const nf4*)(row + k);
      acc = fmaf(v.x, v.x, fmaf(v.y, v.y, fmaf(v.z, v.z, fmaf(v.w, v.w, acc))));
    }
    w2a[s * Kn + c] = acc;
  }
}

// ---------------- main: r16 ping-pong structure + reg-hoisted w2 init ---------
// 256 threads (4 waves). Wave owns a 128-code slice in registers (wA[8][4]).
// D = mfma(A=w, B=x, C=-w^2/2); argmin(w2-2dot) == argmax(D); per-tile result
// via LDS atomicMax of sortable u64 keys into keyb[tile][t].
// r18 lever: acc-init -0.5*w2 hoisted to 8 f32x4 REGISTERS (loop-invariant:
// depends only on wid/g4/ct) — deletes 32 ds_read_b128 per thread per tile
// (half the LDS read traffic of r16). w2L LDS array removed.
// Structure: LDS tile ping-pong (1 barrier/tile), deferred epilogue, setprio.
// launch_bounds(256,1): the ONLY config that avoids spills for this footprint.
__global__ __launch_bounds__(256, 1) void vq4_main(
    const float* __restrict__ x,
    const unsigned short* __restrict__ wPack,
    const float* __restrict__ w2a,
    const float* __restrict__ w0, const float* __restrict__ w1,
    const float* __restrict__ w2_, const float* __restrict__ w3,
    float* __restrict__ out,
    int* __restrict__ idxBuf, float* __restrict__ lossSum)
{
  __shared__ unsigned char tileA[16384];       // x-tile bf16 [t 64][k 128], swizzled
  __shared__ unsigned char tileB[16384];       // ping-pong buffer
  __shared__ unsigned long long keyb[TILES][BRT];  // argmax keys, one buf per tile
  __shared__ float wl[4];

  const int bx  = blockIdx.x;      // 16 tile-groups
  const int b   = blockIdx.y;      // 8
  const int sub = blockIdx.z;      // 4
  const int tid = threadIdx.x;
  const int wid = tid >> 6, lane = tid & 63;
  const int r16_ = lane & 15, g4 = lane >> 4;

  // stage mapping: tid -> (sk8 = tid>>4, sq = tid&15); t = sq*4+j
  const int sq  = tid & 15;
  const int sk8 = tid >> 4;

  const float* xb = x + ((size_t)b * Cn + sub * SUBn) * Tn;
  const unsigned short* wp = wPack + (size_t)sub * Kn * SUBn + lane * 8;
  const float* w2s = w2a + sub * Kn;
  const float* worig = (sub == 0) ? w0 : (sub == 1) ? w1 : (sub == 2) ? w2_ : w3;
  float* outb = out + ((size_t)b * Cn + sub * SUBn) * Tn;
  int* idxOut = idxBuf + ((size_t)b * 4 + sub) * Tn;

  // ---- prologue: zero key buffers ----
  ((unsigned long long*)keyb)[tid] = 0ULL;     // 256 entries = TILES*BRT

  // ---- acc-init constants in REGISTERS (loop-invariant; L2-hot global) ----
  f32x4 w2init[8];
  #pragma unroll
  for (int ct = 0; ct < 8; ++ct) {
    nf4 v = *(const nf4*)(w2s + wid * 128 + ct * 16 + g4 * 4);
    w2init[ct] = -0.5f * v;
  }

  // ---- load this wave's 128-code slice into registers (once per block) ----
  bf16x8 wA[8][4];
  #pragma unroll
  for (int ct = 0; ct < 8; ++ct)
    #pragma unroll
    for (int ks = 0; ks < 4; ++ks)
      wA[ct][ks] = *(const bf16x8*)(wp + (size_t)((wid * 8 + ct) * 4 + ks) * 512);

  float lossAcc = 0.f;

  // ---- prologue: issue tile-0 loads ----
  nf4 P[8];
  {
    const float* src = xb + (size_t)(sk8 * 8) * Tn + (bx * TILES) * BRT + 4 * sq;
    #pragma unroll
    for (int i = 0; i < 8; ++i)
      P[i] = *(const nf4*)(src + (size_t)i * Tn);
  }

  #pragma unroll
  for (int itile = 0; itile < TILES; ++itile) {
    const int t0 = (bx * TILES + itile) * BRT;
    unsigned char* buf = (itile & 1) ? tileB : tileA;

    // ---- P1: cvt P -> bf16 LDS tile (+ sum x^2); issue next tile's loads ----
    {
      float xs = 0.f;
      #pragma unroll
      for (int i = 0; i < 8; ++i)
        xs += P[i].x * P[i].x + P[i].y * P[i].y + P[i].z * P[i].z + P[i].w * P[i].w;
      lossAcc += xs;
      #pragma unroll
      for (int j = 0; j < 4; ++j) {
        int t = 4 * sq + j;
        uint4 pv;
        pv.x = pack2(P[0][j], P[1][j]);
        pv.y = pack2(P[2][j], P[3][j]);
        pv.z = pack2(P[4][j], P[5][j]);
        pv.w = pack2(P[6][j], P[7][j]);
        int waddr = t * 256 + ((sk8 * 16) ^ ((t & 15) << 4));
        *(uint4*)(buf + waddr) = pv;
      }
    }
    if (itile + 1 < TILES) {
      const float* src = xb + (size_t)(sk8 * 8) * Tn + (t0 + BRT) + 4 * sq;
      #pragma unroll
      for (int i = 0; i < 8; ++i)
        P[i] = *(const nf4*)(src + (size_t)i * Tn);
    }
    BARRIER();                      // buf (+ first-iter keyb) ready

    // ---- P2: 4 t-groups; 32 MFMA + tree-argmax + key atomicMax ----
    __builtin_amdgcn_s_setprio(1);
    #pragma unroll
    for (int tg = 0; tg < 4; ++tg) {
      const int t = tg * 16 + r16_;
      bf16x8 xB[4];
      #pragma unroll
      for (int ks = 0; ks < 4; ++ks) {
        int aaddr = t * 256 + ((((ks * 4 + g4) * 16)) ^ (r16_ << 4));
        xB[ks] = *(const bf16x8*)(buf + aaddr);
      }
      f32x4 acc[8];
      #pragma unroll
      for (int ct = 0; ct < 8; ++ct)
        acc[ct] = w2init[ct];                  // register init — no LDS read
      #pragma unroll
      for (int ks = 0; ks < 4; ++ks)
        #pragma unroll
        for (int ct = 0; ct < 8; ++ct)
          acc[ct] = __builtin_amdgcn_mfma_f32_16x16x32_bf16(
              wA[ct][ks], xB[ks], acc[ct], 0, 0, 0);

      // per-ct serial argmax over r (c-ascending, keep-left on ties)
      float cv[8]; int cc_[8];
      #pragma unroll
      for (int ct = 0; ct < 8; ++ct) {
        float bv = acc[ct][0]; int br = ct * 4;
        #pragma unroll
        for (int r = 1; r < 4; ++r)
          if (acc[ct][r] > bv) { bv = acc[ct][r]; br = ct * 4 + r; }
        cv[ct] = bv; cc_[ct] = br;
      }
      // 3-level tree over the 8 ct-chains (c-ascending, keep-left on ties)
      #pragma unroll
      for (int s = 4; s >= 1; s >>= 1)
        #pragma unroll
        for (int i = 0; i < s; ++i)
          if (cv[i + s] > cv[i]) { cv[i] = cv[i + s]; cc_[i] = cc_[i + s]; }

      int code = cc_[0];                        // 0..31 (ct*4+r)
      int bi = wid * 128 + (code >> 2) * 16 + g4 * 4 + (code & 3);
      unsigned long long k64 =
          (unsigned long long)__double_as_longlong((double)cv[0] + 16.0) |
          (unsigned long long)(511 - bi);
      atomicMax(&keyb[itile][t], k64);
    }
    __builtin_amdgcn_s_setprio(0);
    // NO second barrier: next P1 writes the OTHER buffer; BAR(i+1)
    // transitively orders this P2 before any reuse of this buffer at i+2.
  }
  BARRIER();                         // all keys final

  // ---- epilogue: decode keys; idx stores; gather + out stores; loss ----
  #pragma unroll
  for (int itile = 0; itile < TILES; ++itile) {
    const int t0 = (bx * TILES + itile) * BRT;
    const int gt = lane;             // t within tile
    const int kc = wid;              // 32-k chunk per wave
    unsigned long long kk = keyb[itile][gt];
    int bi = 511 - (int)(kk & 0x1FFULL);
    if (tid < BRT) {
      idxOut[t0 + tid] = bi;         // coalesced 256 B plain store
      double vd = __longlong_as_double((long long)(kk & ~0x1FFULL));
      lossAcc += -2.0f * (float)(vd - 16.0);   // min(w2-2s.w) = -2*max(D)
    }
    const float* wrow = worig + (size_t)bi * SUBn + kc * 32;
    float* op = outb + (size_t)(kc * 32) * Tn + t0 + gt;
    #pragma unroll
    for (int i = 0; i < 8; ++i) {
      nf4 wv = *(const nf4*)(wrow + 4 * i);
      op[(size_t)(4 * i + 0) * Tn] = wv.x;
      op[(size_t)(4 * i + 1) * Tn] = wv.y;
      op[(size_t)(4 * i + 2) * Tn] = wv.z;
      op[(size_t)(4 * i + 3) * Tn] = wv.w;
    }
  }

  // ---- block loss reduction -> one atomic ----
  #pragma unroll
  for (int off = 32; off; off >>= 1) lossAcc += __shfl_down(lossAcc, off, 64);
  if (lane == 0) wl[wid] = lossAcc;
  BARRIER();
  if (tid == 0)
    atomicAdd(lossSum, wl[0] + wl[1] + wl[2] + wl[3]);
}

// ---------------- hist: LDS histogram of idxBuf (off main's critical path) ----
__global__ __launch_bounds__(256) void vq4_hist(
    const int* __restrict__ idxBuf, int* __restrict__ hist)
{
  __shared__ int h[512];
  const int b = blockIdx.x >> 2;
  const int s = blockIdx.x & 3;
  const int tid = threadIdx.x;
  h[tid] = 0; h[tid + 256] = 0;
  __syncthreads();
  const int* p = idxBuf + ((size_t)b * 4 + s) * Tn;
  #pragma unroll
  for (int it = 0; it < 4; ++it) {
    int4 v = *(const int4*)(p + 4 * (tid + 256 * it));
    atomicAdd(&h[v.x], 1); atomicAdd(&h[v.y], 1);
    atomicAdd(&h[v.z], 1); atomicAdd(&h[v.w], 1);
  }
  __syncthreads();
  atomicAdd(&hist[s * Kn + tid], h[tid]);
  atomicAdd(&hist[s * Kn + tid + 256], h[tid + 256]);
}

// ---------------- finalize: vq_loss + perplexity ----------------
__global__ __launch_bounds__(256) void vq4_fin(
    const int* __restrict__ hist, const float* __restrict__ lossSum,
    float* __restrict__ out)
{
  const int tid = threadIdx.x;
  float local[4] = {0.f, 0.f, 0.f, 0.f};
  #pragma unroll
  for (int it = 0; it < 8; ++it) {
    int slot = tid + 256 * it;       // 2048 = 4 x 512
    int s = slot >> 9;
    float p = (float)hist[slot] * (1.0f / 32768.0f);
    local[s] += -p * logf(p + 1e-10f);
  }
  __shared__ float red[4][4];
  int lane = tid & 63, wv = tid >> 6;
  #pragma unroll
  for (int s = 0; s < 4; ++s) {
    float v = local[s];
    for (int off = 32; off; off >>= 1) v += __shfl_down(v, off, 64);
    if (lane == 0) red[s][wv] = v;
  }
  __syncthreads();
  if (tid == 0) {
    float loss = 1.25f * lossSum[0] * (1.0f / (float)TOTELEM);
    float perp = 0.f;
    #pragma unroll
    for (int s = 0; s < 4; ++s)
      perp += expf(red[s][0] + red[s][1] + red[s][2] + red[s][3]);
    out[TOTELEM]     = loss;
    out[TOTELEM + 1] = perp;
  }
}

extern "C" void kernel_launch(void* const* d_in, const int* in_sizes, int n_in,
                              void* d_out, int out_size, void* d_ws, size_t ws_size,
                              hipStream_t stream) {
  const float* x  = (const float*)d_in[0];
  const float* w1 = (const float*)d_in[1];
  const float* w2 = (const float*)d_in[2];
  const float* w3 = (const float*)d_in[3];
  const float* w4 = (const float*)d_in[4];
  float* out = (float*)d_out;

  // Disjoint workspace layout
  char* ws = (char*)d_ws;
  float* lossSum = (float*)ws;                            // [0, 16)
  int*   hist    = (int*)(ws + 16);                       // [16, 8208)
  float* w2a     = (float*)(ws + 16384);                  // [16K, 24K)
  unsigned short* wPack = (unsigned short*)(ws + 32768);  // [32K, 544K)
  int*   idxBuf  = (int*)(ws + 1048576);                  // [1M, 1.5M)

  // zero accumulators (hist + lossSum) every call — ws is not re-poisoned
  (void)hipMemsetAsync(d_ws, 0, 8208, stream);

  vq4_pre<<<dim3(32), dim3(256), 0, stream>>>(w1, w2, w3, w4, wPack, w2a);
  vq4_main<<<dim3(Tn / BRT / TILES, Bn, 4), dim3(256), 0, stream>>>(
      x, wPack, w2a, w1, w2, w3, w4, out, idxBuf, lossSum);
  vq4_hist<<<dim3(32), dim3(256), 0, stream>>>(idxBuf, hist);
  vq4_fin<<<dim3(1), dim3(256), 0, stream>>>(hist, lossSum, out);
}

// Round 19
// 59.009 us; speedup vs baseline: 1.2391x; 1.0646x over previous
//
#include <hip/hip_runtime.h>
#include <hip/hip_bf16.h>
#include <float.h>
#include <math.h>

// Problem constants
#define Bn   8
#define Cn   512
#define Tn   4096
#define Kn   512      // codes per sub-codebook
#define SUBn 128      // dims per sub-codebook
#define TOTELEM 16777216  // B*C*T
#define TILES 4       // t-tiles per block (r16/r18 best-known config)
#define BRT  64       // t-rows per tile

typedef __attribute__((ext_vector_type(8))) short bf16x8;   // 8 bf16 = 4 VGPRs
typedef __attribute__((ext_vector_type(4))) float f32x4;    // MFMA acc
typedef __attribute__((ext_vector_type(4))) float nf4;      // native float4

// LDS-only barrier: waits ds ops, leaves vmcnt (global prefetch/stores) in flight.
#define BARRIER() asm volatile("s_waitcnt lgkmcnt(0)\ns_barrier" ::: "memory")

static __device__ inline unsigned int pack2(float a, float b) {
  union { __hip_bfloat162 h; unsigned int u; } cv;
  cv.h = __float22bfloat162_rn(make_float2(a, b));
  return cv.u;
}

// ---------------- precompute: wPack (bf16 fragment order) + ||w||^2 -----------
// Fragment layout (per 16-c block fb = cBlk*16 + ks*4 + g):
//   element offset = fb*128 + (c&15)*8 + (k&7)
__global__ __launch_bounds__(256) void vq4_pre(
    const float* __restrict__ w0, const float* __restrict__ w1,
    const float* __restrict__ w2_, const float* __restrict__ w3,
    unsigned short* __restrict__ wPack, float* __restrict__ w2a)
{
  const int s  = blockIdx.x >> 3;    // sub-codebook
  const int ch = blockIdx.x & 7;     // 64-c chunk
  const int tid = threadIdx.x;
  const float* w = (s == 0) ? w0 : (s == 1) ? w1 : (s == 2) ? w2_ : w3;
  unsigned short* dst = wPack + (size_t)s * Kn * SUBn;

  for (int it = 0; it < 8; ++it) {
    int cell = ch * 2048 + tid + 256 * it;   // 2048 float4 cells per chunk
    int c = cell >> 5;
    int k4 = (cell & 31) * 4;
    nf4 v = *(const nf4*)(w + (size_t)c * SUBn + k4);
    int ks = k4 >> 5, g = (k4 >> 3) & 3, kLo = k4 & 7;
    int fb = (c >> 4) * 16 + ks * 4 + g;
    int off = fb * 128 + (c & 15) * 8 + kLo;
    uint2 p;
    p.x = pack2(v.x, v.y);
    p.y = pack2(v.z, v.w);
    *(uint2*)(dst + off) = p;
  }
  if (tid < 64) {
    int c = ch * 64 + tid;
    const float* row = w + (size_t)c * SUBn;
    float acc = 0.f;
    #pragma unroll
    for (int k = 0; k < SUBn; k += 4) {
      nf4 v = *(const nf4*)(row + k);
      acc = fmaf(v.x, v.x, fmaf(v.y, v.y, fmaf(v.z, v.z, fmaf(v.w, v.w, acc))));
    }
    w2a[s * Kn + c] = acc;
  }
}

// ---------------- main: r18 structure + wide-burst nontemporal out stores -----
// 256 threads (4 waves). Wave owns a 128-code slice in registers (wA[8][4]).
// D = mfma(A=w, B=x, C=-w^2/2); argmin(w2-2dot) == argmax(D); per-tile result
// via LDS atomicMax of sortable u64 keys into keyb[tile][t].
// r19 lever (epilogue only): lane owns 4 CONSECUTIVE t spanning all 4 tiles
// (256 contiguous t per block) -> one float4 NONTEMPORAL store per k = 1 KB
// contiguous per wave-instruction. Fixes the 256 B @16 KB-stride write pattern
// (DRAM row-activation thrash) and keeps the 66 MB write stream out of L3 so
// x stays L3-resident (r12-r18 invariant: 2.0 TB/s mixed-stream bound).
// launch_bounds(256,1): the ONLY config that avoids spills for this footprint.
__global__ __launch_bounds__(256, 1) void vq4_main(
    const float* __restrict__ x,
    const unsigned short* __restrict__ wPack,
    const float* __restrict__ w2a,
    const float* __restrict__ w0, const float* __restrict__ w1,
    const float* __restrict__ w2_, const float* __restrict__ w3,
    float* __restrict__ out,
    int* __restrict__ idxBuf, float* __restrict__ lossSum)
{
  __shared__ unsigned char tileA[16384];       // x-tile bf16 [t 64][k 128], swizzled
  __shared__ unsigned char tileB[16384];       // ping-pong buffer
  __shared__ unsigned long long keyb[TILES][BRT];  // argmax keys, one buf per tile
  __shared__ float wl[4];

  const int bx  = blockIdx.x;      // 16 tile-groups
  const int b   = blockIdx.y;      // 8
  const int sub = blockIdx.z;      // 4
  const int tid = threadIdx.x;
  const int wid = tid >> 6, lane = tid & 63;
  const int r16_ = lane & 15, g4 = lane >> 4;

  // stage mapping: tid -> (sk8 = tid>>4, sq = tid&15); t = sq*4+j
  const int sq  = tid & 15;
  const int sk8 = tid >> 4;

  const float* xb = x + ((size_t)b * Cn + sub * SUBn) * Tn;
  const unsigned short* wp = wPack + (size_t)sub * Kn * SUBn + lane * 8;
  const float* w2s = w2a + sub * Kn;
  const float* worig = (sub == 0) ? w0 : (sub == 1) ? w1 : (sub == 2) ? w2_ : w3;
  float* outb = out + ((size_t)b * Cn + sub * SUBn) * Tn;
  int* idxOut = idxBuf + ((size_t)b * 4 + sub) * Tn;

  // ---- prologue: zero key buffers ----
  ((unsigned long long*)keyb)[tid] = 0ULL;     // 256 entries = TILES*BRT

  // ---- acc-init constants in REGISTERS (loop-invariant; L2-hot global) ----
  f32x4 w2init[8];
  #pragma unroll
  for (int ct = 0; ct < 8; ++ct) {
    nf4 v = *(const nf4*)(w2s + wid * 128 + ct * 16 + g4 * 4);
    w2init[ct] = -0.5f * v;
  }

  // ---- load this wave's 128-code slice into registers (once per block) ----
  bf16x8 wA[8][4];
  #pragma unroll
  for (int ct = 0; ct < 8; ++ct)
    #pragma unroll
    for (int ks = 0; ks < 4; ++ks)
      wA[ct][ks] = *(const bf16x8*)(wp + (size_t)((wid * 8 + ct) * 4 + ks) * 512);

  float lossAcc = 0.f;

  // ---- prologue: issue tile-0 loads ----
  nf4 P[8];
  {
    const float* src = xb + (size_t)(sk8 * 8) * Tn + (bx * TILES) * BRT + 4 * sq;
    #pragma unroll
    for (int i = 0; i < 8; ++i)
      P[i] = *(const nf4*)(src + (size_t)i * Tn);
  }

  #pragma unroll
  for (int itile = 0; itile < TILES; ++itile) {
    const int t0 = (bx * TILES + itile) * BRT;
    unsigned char* buf = (itile & 1) ? tileB : tileA;

    // ---- P1: cvt P -> bf16 LDS tile (+ sum x^2); issue next tile's loads ----
    {
      float xs = 0.f;
      #pragma unroll
      for (int i = 0; i < 8; ++i)
        xs += P[i].x * P[i].x + P[i].y * P[i].y + P[i].z * P[i].z + P[i].w * P[i].w;
      lossAcc += xs;
      #pragma unroll
      for (int j = 0; j < 4; ++j) {
        int t = 4 * sq + j;
        uint4 pv;
        pv.x = pack2(P[0][j], P[1][j]);
        pv.y = pack2(P[2][j], P[3][j]);
        pv.z = pack2(P[4][j], P[5][j]);
        pv.w = pack2(P[6][j], P[7][j]);
        int waddr = t * 256 + ((sk8 * 16) ^ ((t & 15) << 4));
        *(uint4*)(buf + waddr) = pv;
      }
    }
    if (itile + 1 < TILES) {
      const float* src = xb + (size_t)(sk8 * 8) * Tn + (t0 + BRT) + 4 * sq;
      #pragma unroll
      for (int i = 0; i < 8; ++i)
        P[i] = *(const nf4*)(src + (size_t)i * Tn);
    }
    BARRIER();                      // buf (+ first-iter keyb) ready

    // ---- P2: 4 t-groups; 32 MFMA + tree-argmax + key atomicMax ----
    __builtin_amdgcn_s_setprio(1);
    #pragma unroll
    for (int tg = 0; tg < 4; ++tg) {
      const int t = tg * 16 + r16_;
      bf16x8 xB[4];
      #pragma unroll
      for (int ks = 0; ks < 4; ++ks) {
        int aaddr = t * 256 + ((((ks * 4 + g4) * 16)) ^ (r16_ << 4));
        xB[ks] = *(const bf16x8*)(buf + aaddr);
      }
      f32x4 acc[8];
      #pragma unroll
      for (int ct = 0; ct < 8; ++ct)
        acc[ct] = w2init[ct];                  // register init — no LDS read
      #pragma unroll
      for (int ks = 0; ks < 4; ++ks)
        #pragma unroll
        for (int ct = 0; ct < 8; ++ct)
          acc[ct] = __builtin_amdgcn_mfma_f32_16x16x32_bf16(
              wA[ct][ks], xB[ks], acc[ct], 0, 0, 0);

      // per-ct serial argmax over r (c-ascending, keep-left on ties)
      float cv[8]; int cc_[8];
      #pragma unroll
      for (int ct = 0; ct < 8; ++ct) {
        float bv = acc[ct][0]; int br = ct * 4;
        #pragma unroll
        for (int r = 1; r < 4; ++r)
          if (acc[ct][r] > bv) { bv = acc[ct][r]; br = ct * 4 + r; }
        cv[ct] = bv; cc_[ct] = br;
      }
      // 3-level tree over the 8 ct-chains (c-ascending, keep-left on ties)
      #pragma unroll
      for (int s = 4; s >= 1; s >>= 1)
        #pragma unroll
        for (int i = 0; i < s; ++i)
          if (cv[i + s] > cv[i]) { cv[i] = cv[i + s]; cc_[i] = cc_[i + s]; }

      int code = cc_[0];                        // 0..31 (ct*4+r)
      int bi = wid * 128 + (code >> 2) * 16 + g4 * 4 + (code & 3);
      unsigned long long k64 =
          (unsigned long long)__double_as_longlong((double)cv[0] + 16.0) |
          (unsigned long long)(511 - bi);
      atomicMax(&keyb[itile][t], k64);
    }
    __builtin_amdgcn_s_setprio(0);
    // NO second barrier: next P1 writes the OTHER buffer; BAR(i+1)
    // transitively orders this P2 before any reuse of this buffer at i+2.
  }
  BARRIER();                         // all keys final

  // ---- epilogue A: idx stores + loss (tid<64, per tile) ----
  #pragma unroll
  for (int itile = 0; itile < TILES; ++itile) {
    if (tid < BRT) {
      unsigned long long kk = keyb[itile][tid];
      int bi = 511 - (int)(kk & 0x1FFULL);
      idxOut[(bx * TILES + itile) * BRT + tid] = bi;
      double vd = __longlong_as_double((long long)(kk & ~0x1FFULL));
      lossAcc += -2.0f * (float)(vd - 16.0);   // min(w2-2s.w) = -2*max(D)
    }
  }

  // ---- epilogue B: gather + WIDE nontemporal out stores ----
  // lane owns 4 consecutive t across the block's 256-t span; per k-step one
  // float4 nt store -> 1 KB contiguous per wave-instruction.
  {
    const int tloc  = lane << 2;               // 0..252 within block span
    const int itile = lane >> 4;               // which keyb buffer
    const int tsub  = tloc & 63;               // t within tile (multiple of 4)
    const int kc    = wid;                     // 32-k chunk per wave
    const int tbase = bx * TILES * BRT;        // block's t origin

    int bi4[4];
    #pragma unroll
    for (int j = 0; j < 4; ++j)
      bi4[j] = 511 - (int)(keyb[itile][tsub + j] & 0x1FFULL);

    const float* r0 = worig + (size_t)bi4[0] * SUBn + kc * 32;
    const float* r1 = worig + (size_t)bi4[1] * SUBn + kc * 32;
    const float* r2 = worig + (size_t)bi4[2] * SUBn + kc * 32;
    const float* r3 = worig + (size_t)bi4[3] * SUBn + kc * 32;
    float* op = outb + (size_t)(kc * 32) * Tn + tbase + tloc;
    #pragma unroll
    for (int i = 0; i < 32; ++i) {
      nf4 o = {r0[i], r1[i], r2[i], r3[i]};
      __builtin_nontemporal_store(o, (nf4*)(op + (size_t)i * Tn));
    }
  }

  // ---- block loss reduction -> one atomic ----
  #pragma unroll
  for (int off = 32; off; off >>= 1) lossAcc += __shfl_down(lossAcc, off, 64);
  if (lane == 0) wl[wid] = lossAcc;
  BARRIER();
  if (tid == 0)
    atomicAdd(lossSum, wl[0] + wl[1] + wl[2] + wl[3]);
}

// ---------------- hist: LDS histogram of idxBuf (off main's critical path) ----
__global__ __launch_bounds__(256) void vq4_hist(
    const int* __restrict__ idxBuf, int* __restrict__ hist)
{
  __shared__ int h[512];
  const int b = blockIdx.x >> 2;
  const int s = blockIdx.x & 3;
  const int tid = threadIdx.x;
  h[tid] = 0; h[tid + 256] = 0;
  __syncthreads();
  const int* p = idxBuf + ((size_t)b * 4 + s) * Tn;
  #pragma unroll
  for (int it = 0; it < 4; ++it) {
    int4 v = *(const int4*)(p + 4 * (tid + 256 * it));
    atomicAdd(&h[v.x], 1); atomicAdd(&h[v.y], 1);
    atomicAdd(&h[v.z], 1); atomicAdd(&h[v.w], 1);
  }
  __syncthreads();
  atomicAdd(&hist[s * Kn + tid], h[tid]);
  atomicAdd(&hist[s * Kn + tid + 256], h[tid + 256]);
}

// ---------------- finalize: vq_loss + perplexity ----------------
__global__ __launch_bounds__(256) void vq4_fin(
    const int* __restrict__ hist, const float* __restrict__ lossSum,
    float* __restrict__ out)
{
  const int tid = threadIdx.x;
  float local[4] = {0.f, 0.f, 0.f, 0.f};
  #pragma unroll
  for (int it = 0; it < 8; ++it) {
    int slot = tid + 256 * it;       // 2048 = 4 x 512
    int s = slot >> 9;
    float p = (float)hist[slot] * (1.0f / 32768.0f);
    local[s] += -p * logf(p + 1e-10f);
  }
  __shared__ float red[4][4];
  int lane = tid & 63, wv = tid >> 6;
  #pragma unroll
  for (int s = 0; s < 4; ++s) {
    float v = local[s];
    for (int off = 32; off; off >>= 1) v += __shfl_down(v, off, 64);
    if (lane == 0) red[s][wv] = v;
  }
  __syncthreads();
  if (tid == 0) {
    float loss = 1.25f * lossSum[0] * (1.0f / (float)TOTELEM);
    float perp = 0.f;
    #pragma unroll
    for (int s = 0; s < 4; ++s)
      perp += expf(red[s][0] + red[s][1] + red[s][2] + red[s][3]);
    out[TOTELEM]     = loss;
    out[TOTELEM + 1] = perp;
  }
}

extern "C" void kernel_launch(void* const* d_in, const int* in_sizes, int n_in,
                              void* d_out, int out_size, void* d_ws, size_t ws_size,
                              hipStream_t stream) {
  const float* x  = (const float*)d_in[0];
  const float* w1 = (const float*)d_in[1];
  const float* w2 = (const float*)d_in[2];
  const float* w3 = (const float*)d_in[3];
  const float* w4 = (const float*)d_in[4];
  float* out = (float*)d_out;

  // Disjoint workspace layout
  char* ws = (char*)d_ws;
  float* lossSum = (float*)ws;                            // [0, 16)
  int*   hist    = (int*)(ws + 16);                       // [16, 8208)
  float* w2a     = (float*)(ws + 16384);                  // [16K, 24K)
  unsigned short* wPack = (unsigned short*)(ws + 32768);  // [32K, 544K)
  int*   idxBuf  = (int*)(ws + 1048576);                  // [1M, 1.5M)

  // zero accumulators (hist + lossSum) every call — ws is not re-poisoned
  (void)hipMemsetAsync(d_ws, 0, 8208, stream);

  vq4_pre<<<dim3(32), dim3(256), 0, stream>>>(w1, w2, w3, w4, wPack, w2a);
  vq4_main<<<dim3(Tn / BRT / TILES, Bn, 4), dim3(256), 0, stream>>>(
      x, wPack, w2a, w1, w2, w3, w4, out, idxBuf, lossSum);
  vq4_hist<<<dim3(32), dim3(256), 0, stream>>>(idxBuf, hist);
  vq4_fin<<<dim3(1), dim3(256), 0, stream>>>(hist, lossSum, out);
}